// Round 1
// baseline (437.320 us; speedup 1.0000x reference)
//
#include <hip/hip_runtime.h>

// Problem: out = adj1*in1 + adj2*in2 + adj3*(in1+in2) where adj flags come from
// comparing sigmoid(mean(conv3x3(in_k))) per channel. Mean-of-conv collapses to
// 9 window sums per channel (linear in input), so no actual conv is needed.
//
// C=256, H=W=384, conv VALID -> 382x382 output, mean divisor 382^2=145924.

#define CH 256
#define WD 384
#define ROW_F4 96              // 384 / 4
#define CH_F4 (WD * WD / 4)    // 36864 float4 per channel
#define CH_ELEMS (WD * WD)     // 147456

__device__ inline double wave_reduce(double v) {
    #pragma unroll
    for (int off = 32; off > 0; off >>= 1)
        v += __shfl_down(v, off, 64);
    return v;
}

// K1: per (input, channel) compute the 9 window sums S[kh][kw] = sum of the
// 382x382 window starting at (kh,kw). Derived from: total sum T, edge column
// sums C0,C1,C382,C383, edge row sums R0,R1,R382,R383, and 16 corner elements.
__global__ __launch_bounds__(256) void sums_kernel(
    const float* __restrict__ in1, const float* __restrict__ in2,
    double* __restrict__ S /* [2][256][9] */)
{
    int bid = blockIdx.x;          // 0..511
    int inp = bid >> 8;            // 0 or 1
    int c   = bid & 255;
    const float* base = (inp ? in2 : in1) + (size_t)c * CH_ELEMS;
    const float4* p = (const float4*)base;
    int tid = threadIdx.x;

    double T = 0, C0 = 0, C1 = 0, C382 = 0, C383 = 0;
    double R0 = 0, R1 = 0, R382 = 0, R383 = 0;

    for (int i = tid; i < CH_F4; i += 256) {
        float4 v = p[i];
        int r  = i / ROW_F4;
        int c4 = i - r * ROW_F4;
        double s = ((double)v.x + (double)v.y) + ((double)v.z + (double)v.w);
        T += s;
        if (c4 == 0)          { C0   += (double)v.x; C1   += (double)v.y; }
        if (c4 == ROW_F4 - 1) { C382 += (double)v.z; C383 += (double)v.w; }
        if      (r == 0)      R0   += s;
        else if (r == 1)      R1   += s;
        else if (r == WD - 2) R382 += s;
        else if (r == WD - 1) R383 += s;
    }

    __shared__ double red[4][9];
    double vals[9] = {T, C0, C1, C382, C383, R0, R1, R382, R383};
    int lane = tid & 63, wv = tid >> 6;
    #pragma unroll
    for (int k = 0; k < 9; k++) {
        double r = wave_reduce(vals[k]);
        if (lane == 0) red[wv][k] = r;
    }
    __syncthreads();

    if (tid == 0) {
        double a[9];
        #pragma unroll
        for (int k = 0; k < 9; k++)
            a[k] = (red[0][k] + red[1][k]) + (red[2][k] + red[3][k]);
        double Tt = a[0], c0 = a[1], c1 = a[2], c382 = a[3], c383 = a[4];
        double r0 = a[5], r1 = a[6], r382 = a[7], r383 = a[8];

        // 16 corner elements (L2-hot: this block just streamed the channel)
        double x00 = base[0*WD+0],   x01 = base[0*WD+1],   x0a = base[0*WD+382],   x0b = base[0*WD+383];
        double x10 = base[1*WD+0],   x11 = base[1*WD+1],   x1a = base[1*WD+382],   x1b = base[1*WD+383];
        double xa0 = base[382*WD+0], xa1 = base[382*WD+1], xaa = base[382*WD+382], xab = base[382*WD+383];
        double xb0 = base[383*WD+0], xb1 = base[383*WD+1], xba = base[383*WD+382], xbb = base[383*WD+383];

        // Tot[kw]: all-rows sum restricted to cols [kw, kw+382)
        double Tot[3] = { Tt - c382 - c383, Tt - c0 - c383, Tt - c0 - c1 };
        // rowpart[r][kw]: row r restricted to cols [kw, kw+382)
        double rp0[3] = { r0 - x0a - x0b,   r0 - x00 - x0b,   r0 - x00 - x01 };
        double rp1[3] = { r1 - x1a - x1b,   r1 - x10 - x1b,   r1 - x10 - x11 };
        double rpa[3] = { r382 - xaa - xab, r382 - xa0 - xab, r382 - xa0 - xa1 };
        double rpb[3] = { r383 - xba - xbb, r383 - xb0 - xbb, r383 - xb0 - xb1 };

        double* out = S + ((size_t)inp * CH + c) * 9;
        #pragma unroll
        for (int kw = 0; kw < 3; kw++) {
            out[0*3 + kw] = Tot[kw] - rpa[kw] - rpb[kw];  // kh=0: rows 0..381
            out[1*3 + kw] = Tot[kw] - rp0[kw] - rpb[kw];  // kh=1: rows 1..382
            out[2*3 + kw] = Tot[kw] - rp0[kw] - rp1[kw];  // kh=2: rows 2..383
        }
    }
}

// K2: y1 = W·S1, y2 = W·S2 (256 x 2304 dual matvec, fp64), then per-channel
// branch flags on the pre-sigmoid means (sigmoid is strictly monotonic, so
// comparisons on x are identical to comparisons on m). Emit k1, k2 with
// out = k1*in1 + k2*in2  (k1 = adj1+adj3, k2 = adj2+adj3).
__global__ __launch_bounds__(256) void coef_kernel(
    const float* __restrict__ Wt, const float* __restrict__ b,
    const double* __restrict__ S, float* __restrict__ K /* [256][2] */)
{
    int co = blockIdx.x;
    int tid = threadIdx.x;
    const float*  wrow = Wt + (size_t)co * 2304;
    const double* S1 = S;            // [ci*9 + kh*3 + kw], matches W row layout
    const double* S2 = S + 2304;
    double y1 = 0, y2 = 0;
    for (int j = tid; j < 2304; j += 256) {
        double w = (double)wrow[j];
        y1 += w * S1[j];
        y2 += w * S2[j];
    }
    __shared__ double red[4][2];
    int lane = tid & 63, wv = tid >> 6;
    y1 = wave_reduce(y1);
    y2 = wave_reduce(y2);
    if (lane == 0) { red[wv][0] = y1; red[wv][1] = y2; }
    __syncthreads();
    if (tid == 0) {
        double Y1 = (red[0][0] + red[1][0]) + (red[2][0] + red[3][0]);
        double Y2 = (red[0][1] + red[1][1]) + (red[2][1] + red[3][1]);
        const double inv = 1.0 / 145924.0;   // 382*382
        double bb = (double)b[co];
        double m1 = bb + Y1 * inv;
        double m2 = bb + Y2 * inv;
        double m3 = bb + (Y1 + Y2) * inv;
        bool c1 = (m1 >= m2), c2 = (m1 <= m2);
        float adj1 = (c1 && m1 >= m3) ? 1.0f : 0.0f;
        float adj2 = (c2 && m2 >= m3) ? 1.0f : 0.0f;
        float adj3 = ((c1 && m1 < m3) || (c2 && m2 < m3)) ? 1.0f : 0.0f;
        K[2*co]     = adj1 + adj3;
        K[2*co + 1] = adj2 + adj3;
    }
}

// K3: out = k1[c]*in1 + k2[c]*in2, float4 vectorized, perfectly coalesced.
__global__ __launch_bounds__(256) void mix_kernel(
    const float* __restrict__ in1, const float* __restrict__ in2,
    const float* __restrict__ K, float* __restrict__ out)
{
    int c = blockIdx.y;
    size_t idx = (size_t)c * CH_F4 + (size_t)blockIdx.x * 256 + threadIdx.x;
    const float4* a4 = (const float4*)in1;
    const float4* b4 = (const float4*)in2;
    float4* o4 = (float4*)out;
    float k1 = K[2*c], k2 = K[2*c + 1];   // blockIdx-uniform -> scalar loads
    float4 a = a4[idx], bv = b4[idx];
    float4 o;
    o.x = k1*a.x + k2*bv.x;
    o.y = k1*a.y + k2*bv.y;
    o.z = k1*a.z + k2*bv.z;
    o.w = k1*a.w + k2*bv.w;
    o4[idx] = o;
}

extern "C" void kernel_launch(void* const* d_in, const int* in_sizes, int n_in,
                              void* d_out, int out_size, void* d_ws, size_t ws_size,
                              hipStream_t stream) {
    const float* in1 = (const float*)d_in[0];
    const float* in2 = (const float*)d_in[1];
    const float* Wt  = (const float*)d_in[2];
    const float* b   = (const float*)d_in[3];
    float* out = (float*)d_out;

    double* S = (double*)d_ws;                                  // 2*256*9 doubles = 36864 B
    float*  K = (float*)((char*)d_ws + 2 * CH * 9 * sizeof(double)); // 512 floats

    sums_kernel<<<512, 256, 0, stream>>>(in1, in2, S);
    coef_kernel<<<CH, 256, 0, stream>>>(Wt, b, S, K);
    mix_kernel<<<dim3(CH_F4 / 256, CH), 256, 0, stream>>>(in1, in2, K, out);
}

// Round 3
// 404.960 us; speedup vs baseline: 1.0799x; 1.0799x over previous
//
#include <hip/hip_runtime.h>

// out = k1[c]*in1 + k2[c]*in2 where k's come from comparing pre-sigmoid
// channel means of conv3x3(in_k). Mean-of-conv collapses to 9 window sums per
// channel (linear in input) -> no conv needed. Sigmoid monotonic -> compare
// pre-sigmoid means. C=256, H=W=384, VALID -> 382x382, divisor 382^2.

#define CH 256
#define WD 384
#define ROW_F4 96               // 384/4 float4 per row
#define CH_F4 (WD * WD / 4)     // 36864 float4 per channel
#define CH_ELEMS (WD * WD)      // 147456
#define NCHUNK 4
#define CHUNK_ROWS 96
#define CHUNK_F4 (CHUNK_ROWS * ROW_F4)   // 9216 float4 per chunk

typedef float v4f __attribute__((ext_vector_type(4)));  // native vector for nontemporal builtins

__device__ inline double wave_reduce(double v) {
    #pragma unroll
    for (int off = 32; off > 0; off >>= 1)
        v += __shfl_down(v, off, 64);
    return v;
}

// Stage A: per (input, channel, 96-row chunk) partial sums of the 9 reduction
// quantities. Hot loop is branch-free: pure float4 load + f64 accumulate.
// Edge columns/rows are re-read in tiny side loops (L2-hot, negligible bytes).
__global__ __launch_bounds__(256) void sumsA_kernel(
    const float* __restrict__ in1, const float* __restrict__ in2,
    double* __restrict__ P /* [2*256*4][9] */)
{
    int bid   = blockIdx.x;          // [inp(2)][c(256)][chunk(4)]
    int chunk = bid & 3;
    int c     = (bid >> 2) & 255;
    int inp   = bid >> 10;
    const float4* p = (const float4*)((inp ? in2 : in1) + (size_t)c * CH_ELEMS)
                      + (size_t)chunk * CHUNK_F4;
    int tid = threadIdx.x;

    // main loop: 36 independent loads per thread, 2 accumulators for ILP
    double T0 = 0, T1 = 0;
    #pragma unroll
    for (int k = 0; k < 36; k += 2) {
        float4 v0 = p[tid + k * 256];
        float4 v1 = p[tid + (k + 1) * 256];
        T0 += ((double)v0.x + (double)v0.y) + ((double)v0.z + (double)v0.w);
        T1 += ((double)v1.x + (double)v1.y) + ((double)v1.z + (double)v1.w);
    }
    double T = T0 + T1;

    // edge columns of this chunk's 96 rows (cols 0,1 and 382,383)
    double C0 = 0, C1 = 0, C382 = 0, C383 = 0;
    if (tid < CHUNK_ROWS) {
        float4 a = p[tid * ROW_F4];
        float4 z = p[tid * ROW_F4 + ROW_F4 - 1];
        C0 = a.x; C1 = a.y; C382 = z.z; C383 = z.w;
    }
    // edge rows (global rows 0,1 in chunk 0; 382,383 in chunk 3)
    double R0 = 0, R1 = 0, R382 = 0, R383 = 0;
    if (chunk == 0 && tid < 2 * ROW_F4) {
        float4 v = p[tid];
        double s = ((double)v.x + (double)v.y) + ((double)v.z + (double)v.w);
        if (tid < ROW_F4) R0 = s; else R1 = s;
    }
    if (chunk == 3 && tid < 2 * ROW_F4) {
        float4 v = p[CHUNK_F4 - 2 * ROW_F4 + tid];
        double s = ((double)v.x + (double)v.y) + ((double)v.z + (double)v.w);
        if (tid < ROW_F4) R382 = s; else R383 = s;
    }

    __shared__ double red[4][9];
    double vals[9] = {T, C0, C1, C382, C383, R0, R1, R382, R383};
    int lane = tid & 63, wv = tid >> 6;
    #pragma unroll
    for (int k = 0; k < 9; k++) {
        double r = wave_reduce(vals[k]);
        if (lane == 0) red[wv][k] = r;
    }
    __syncthreads();
    if (tid < 9) {
        P[(size_t)bid * 9 + tid] =
            (red[0][tid] + red[1][tid]) + (red[2][tid] + red[3][tid]);
    }
}

// Stage B: combine 4 chunk partials per (input, channel), add corner terms,
// emit the 9 window sums S[kh][kw]. Deterministic (fixed tree).
__global__ __launch_bounds__(64) void sumsB_kernel(
    const float* __restrict__ in1, const float* __restrict__ in2,
    const double* __restrict__ P, double* __restrict__ S /* [2][256][9] */)
{
    int b = blockIdx.x;             // [inp][c]
    int inp = b >> 8, c = b & 255;
    int tid = threadIdx.x;
    __shared__ double a[9];
    if (tid < 9) {
        const double* pp = P + (size_t)b * 36 + tid;
        a[tid] = (pp[0] + pp[9]) + (pp[18] + pp[27]);
    }
    __syncthreads();
    if (tid == 0) {
        const float* base = (inp ? in2 : in1) + (size_t)c * CH_ELEMS;
        double Tt = a[0], c0 = a[1], c1 = a[2], c382 = a[3], c383 = a[4];
        double r0 = a[5], r1 = a[6], r382 = a[7], r383 = a[8];

        double x00 = base[0*WD+0],   x01 = base[0*WD+1],   x0a = base[0*WD+382],   x0b = base[0*WD+383];
        double x10 = base[1*WD+0],   x11 = base[1*WD+1],   x1a = base[1*WD+382],   x1b = base[1*WD+383];
        double xa0 = base[382*WD+0], xa1 = base[382*WD+1], xaa = base[382*WD+382], xab = base[382*WD+383];
        double xb0 = base[383*WD+0], xb1 = base[383*WD+1], xba = base[383*WD+382], xbb = base[383*WD+383];

        double Tot[3] = { Tt - c382 - c383, Tt - c0 - c383, Tt - c0 - c1 };
        double rp0[3] = { r0 - x0a - x0b,   r0 - x00 - x0b,   r0 - x00 - x01 };
        double rp1[3] = { r1 - x1a - x1b,   r1 - x10 - x1b,   r1 - x10 - x11 };
        double rpa[3] = { r382 - xaa - xab, r382 - xa0 - xab, r382 - xa0 - xa1 };
        double rpb[3] = { r383 - xba - xbb, r383 - xb0 - xbb, r383 - xb0 - xb1 };

        double* out = S + (size_t)b * 9;
        #pragma unroll
        for (int kw = 0; kw < 3; kw++) {
            out[0*3 + kw] = Tot[kw] - rpa[kw] - rpb[kw];
            out[1*3 + kw] = Tot[kw] - rp0[kw] - rpb[kw];
            out[2*3 + kw] = Tot[kw] - rp0[kw] - rp1[kw];
        }
    }
}

// y1 = W*S1, y2 = W*S2 (fp64 dual matvec), branch flags on pre-sigmoid means.
__global__ __launch_bounds__(256) void coef_kernel(
    const float* __restrict__ Wt, const float* __restrict__ b,
    const double* __restrict__ S, float* __restrict__ K /* [256][2] */)
{
    int co = blockIdx.x;
    int tid = threadIdx.x;
    const float*  wrow = Wt + (size_t)co * 2304;
    const double* S1 = S;
    const double* S2 = S + 2304;
    double y1 = 0, y2 = 0;
    for (int j = tid; j < 2304; j += 256) {
        double w = (double)wrow[j];
        y1 += w * S1[j];
        y2 += w * S2[j];
    }
    __shared__ double red[4][2];
    int lane = tid & 63, wv = tid >> 6;
    y1 = wave_reduce(y1);
    y2 = wave_reduce(y2);
    if (lane == 0) { red[wv][0] = y1; red[wv][1] = y2; }
    __syncthreads();
    if (tid == 0) {
        double Y1 = (red[0][0] + red[1][0]) + (red[2][0] + red[3][0]);
        double Y2 = (red[0][1] + red[1][1]) + (red[2][1] + red[3][1]);
        const double inv = 1.0 / 145924.0;
        double bb = (double)b[co];
        double m1 = bb + Y1 * inv;
        double m2 = bb + Y2 * inv;
        double m3 = bb + (Y1 + Y2) * inv;
        bool c1 = (m1 >= m2), c2 = (m1 <= m2);
        float adj1 = (c1 && m1 >= m3) ? 1.0f : 0.0f;
        float adj2 = (c2 && m2 >= m3) ? 1.0f : 0.0f;
        float adj3 = ((c1 && m1 < m3) || (c2 && m2 < m3)) ? 1.0f : 0.0f;
        K[2*co]     = adj1 + adj3;
        K[2*co + 1] = adj2 + adj3;
    }
}

// out = k1[c]*in1 + k2[c]*in2. 2x float4 per thread, nontemporal stores
// (write-once stream; keep L2/L3 for the read streams).
__global__ __launch_bounds__(256) void mix_kernel(
    const float* __restrict__ in1, const float* __restrict__ in2,
    const float* __restrict__ K, float* __restrict__ out)
{
    int c = blockIdx.y;
    size_t idx = (size_t)c * CH_F4 + (size_t)blockIdx.x * 512 + threadIdx.x;
    const float4* a4 = (const float4*)in1;
    const float4* b4 = (const float4*)in2;
    v4f* o4 = (v4f*)out;
    float k1 = K[2*c], k2 = K[2*c + 1];
    float4 a0 = a4[idx],       b0 = b4[idx];
    float4 a1 = a4[idx + 256], b1 = b4[idx + 256];
    v4f o0, o1;
    o0.x = k1*a0.x + k2*b0.x; o0.y = k1*a0.y + k2*b0.y;
    o0.z = k1*a0.z + k2*b0.z; o0.w = k1*a0.w + k2*b0.w;
    o1.x = k1*a1.x + k2*b1.x; o1.y = k1*a1.y + k2*b1.y;
    o1.z = k1*a1.z + k2*b1.z; o1.w = k1*a1.w + k2*b1.w;
    __builtin_nontemporal_store(o0, &o4[idx]);
    __builtin_nontemporal_store(o1, &o4[idx + 256]);
}

extern "C" void kernel_launch(void* const* d_in, const int* in_sizes, int n_in,
                              void* d_out, int out_size, void* d_ws, size_t ws_size,
                              hipStream_t stream) {
    const float* in1 = (const float*)d_in[0];
    const float* in2 = (const float*)d_in[1];
    const float* Wt  = (const float*)d_in[2];
    const float* b   = (const float*)d_in[3];
    float* out = (float*)d_out;

    double* P = (double*)d_ws;                                   // 2*256*4*9*8 = 147456 B
    double* S = (double*)((char*)d_ws + 2 * CH * NCHUNK * 9 * sizeof(double)); // 36864 B
    float*  K = (float*)((char*)S + 2 * CH * 9 * sizeof(double));

    sumsA_kernel<<<2 * CH * NCHUNK, 256, 0, stream>>>(in1, in2, P);
    sumsB_kernel<<<2 * CH, 64, 0, stream>>>(in1, in2, P, S);
    coef_kernel<<<CH, 256, 0, stream>>>(Wt, b, S, K);
    mix_kernel<<<dim3(CH_F4 / 512, CH), 256, 0, stream>>>(in1, in2, K, out);
}